// Round 7
// baseline (101.793 us; speedup 1.0000x reference)
//
#include <hip/hip_runtime.h>
#include <hip/hip_bf16.h>
#include <hip/hip_fp8.h>
#include <math.h>

typedef float f32x4 __attribute__((ext_vector_type(4)));
typedef int   i32x4 __attribute__((ext_vector_type(4)));
typedef int   v8i   __attribute__((ext_vector_type(8)));

constexpr int Nn = 8192;   // B*S
constexpr int Dd = 256;    // feature dim (== bytes per fp8 row)
constexpr float LOG2E     = 1.4426950408889634f;
constexpr float SIM_SCALE = 20.0f * LOG2E;   // (1/tau)*log2(e), tau=0.05
constexpr float SIM_BIAS  = -20.0f * LOG2E;  // fixed max = 1/tau (|q.k|<=1)
constexpr int   SCALE1    = 0x7F7F7F7F;      // E8M0 127 = 2^0 in every byte

// async global->LDS DMA, 16B/lane; LDS dst = wave-uniform base + lane*16.
typedef __attribute__((address_space(1))) const unsigned int gu32;
typedef __attribute__((address_space(3))) unsigned int lu32;
__device__ __forceinline__ void gload16(const unsigned char* g, unsigned char* l) {
  __builtin_amdgcn_global_load_lds((gu32*)(uintptr_t)g, (lu32*)(uintptr_t)l, 16, 0, 0);
}

#define VMCNT2() asm volatile("s_waitcnt vmcnt(2)" ::: "memory")
#define VMCNT6() asm volatile("s_waitcnt vmcnt(6)" ::: "memory")
#define VMCNT0() asm volatile("s_waitcnt vmcnt(0)" ::: "memory")
#define LGKM0()  asm volatile("s_waitcnt lgkmcnt(0)" ::: "memory")
#define SCHEDB() __builtin_amdgcn_sched_barrier(0)
#define BAR()    __builtin_amdgcn_s_barrier()

// ---------------------------------------------------------------------------
// Kernel 1: L2-normalize rows -> fp8 e4m3; init cbias (SIM_BIAS pre-folded) /
// g_all / g_pos.  (Correctness-verified, unchanged.)
// ---------------------------------------------------------------------------
__global__ __launch_bounds__(256) void prep_kernel(const float* __restrict__ logits,
                                                   const float* __restrict__ labels,
                                                   const int* __restrict__ pad,
                                                   unsigned char* __restrict__ qb,
                                                   unsigned char* __restrict__ kb,
                                                   float* __restrict__ cbias,
                                                   float* __restrict__ g_all,
                                                   float* __restrict__ g_pos) {
  const int j = blockIdx.x * 256 + threadIdx.x;
  if (j < Nn) {
    cbias[j] = pad[j] ? SIM_BIAS : -1e30f;   // SIM_BIAS folded in (col term)
    g_all[j] = 0.0f;
    g_pos[j] = 0.0f;
  }

  const int gw   = (blockIdx.x * 256 + threadIdx.x) >> 6;
  const int lane = threadIdx.x & 63;
  const float* src;
  unsigned char* dst;
  int row;
  if (gw < Nn) { src = logits; dst = qb; row = gw; }
  else         { src = labels; dst = kb; row = gw - Nn; }

  const float4 v = *reinterpret_cast<const float4*>(src + (size_t)row * Dd + lane * 4);
  float ss = v.x * v.x + v.y * v.y + v.z * v.z + v.w * v.w;
#pragma unroll
  for (int m = 32; m >= 1; m >>= 1) ss += __shfl_xor(ss, m);
  const float scale = 1.0f / fmaxf(sqrtf(ss), 1e-12f);

  const __hip_fp8_e4m3 e0(v.x * scale);
  const __hip_fp8_e4m3 e1(v.y * scale);
  const __hip_fp8_e4m3 e2(v.z * scale);
  const __hip_fp8_e4m3 e3(v.w * scale);
  const unsigned int packed = (unsigned int)e0.__x |
                              ((unsigned int)e1.__x << 8) |
                              ((unsigned int)e2.__x << 16) |
                              ((unsigned int)e3.__x << 24);
  reinterpret_cast<unsigned int*>(dst + (size_t)row * Dd)[lane] = packed;
}

// ---------------------------------------------------------------------------
// Kernel 2 (R20): occupancy attack with honest register math.
// Block = 64 rows x 1024 cols; grid (128,8) = 1024 blocks = 4/CU exactly.
//   - LDS = A(16KB resident) + B-ring 3 x 8KB (64col x 128B kk-half tiles)
//     = 40960 B -> 4 blocks/CU (4 x 40960 = 160 KiB exactly).
//   - true reg need ~110 (afReg 32, c 16, ap 16, rowAd 8, meta 4, misc ~30)
//     -> __launch_bounds__(256,4) budget 128 with ~+18 margin (R18's spill
//     cliff was a -60 margin; this is the opposite sign).
//   - counted-vmcnt ring, R19-verified scheme re-derived for 2-load stages +
//     4-load metas: even phase vmcnt(2), odd vmcnt(6), last vmcnt(0);
//     LGKM0+sched_barrier(0) pins each phase's ds_reads (rule #18).
//   - swizzles: A slot = g ^ (row&3) in 256B rows (one-time hoist);
//     B slot = g ^ (col&7) in 128B rows -> fragment formulas identical to
//     the R13..R19-verified path.
// Waves/SIMD 2 -> 4; MFMA count per SIMD unchanged.
// ---------------------------------------------------------------------------
__global__ __launch_bounds__(256, 4) void gemm_lse_kernel(const unsigned char* __restrict__ qb,
                                                          const unsigned char* __restrict__ kb,
                                                          const float* __restrict__ cbias,
                                                          const int* __restrict__ ad,
                                                          float* __restrict__ g_all,
                                                          float* __restrict__ g_pos) {
  __shared__ unsigned char smem[40960];
  // A: [0,16384): 64 rows x 256B.  B ring: 16384 + slot*8192, slot = tile%3.

  const int tid  = threadIdx.x;
  const int lane = tid & 63;
  const int w    = tid >> 6;   // 0..3
  const int wr   = w >> 1;     // row half: rows wr*32..+32
  const int wc   = w & 1;      // col half within 64-col tile: wc*32..+32
  const int lq   = lane & 15;
  const int qd   = lane >> 4;
  const int rowBase = blockIdx.x * 64;
  const int colBase = blockIdx.y * 1024;   // 16 col-tiles of 64

  // ---- A staging (one-time): call i fills rows [w*16+i*4,+4) = 1KB contig;
  // lane l -> row +(l>>4), slot l&15 <- group (l&15)^(l>>4)  (row&3 == l>>4).
  const unsigned char* gA = qb + (size_t)(rowBase + w * 16 + (lane >> 4)) * Dd
                               + (((lane & 15) ^ (lane >> 4)) << 4);
#pragma unroll
  for (int i = 0; i < 4; ++i)
    gload16(gA + i * 1024, &smem[w * 4096 + i * 1024]);

  // ---- B staging: tile t = (col-tile t>>1, kk-half t&1), 64 cols x 128B.
  // call i fills cols [w*16+i*8,+8); lane l -> col +(l>>3), slot l&7 <-
  // group (l&7)^(l>>3)  (col&7 == l>>3).
  const unsigned char* gB = kb + (size_t)(colBase + w * 16 + (lane >> 3)) * Dd
                               + (((lane & 7) ^ (lane >> 3)) << 4);

#define STAGE_B(t, slot) do {                                         \
    unsigned char* dB_ = &smem[16384 + (slot) * 8192 + w * 2048];     \
    const unsigned char* gS_ = gB + ((t) >> 1) * 16384 + ((t) & 1) * 128; \
    gload16(gS_,        dB_);                                         \
    gload16(gS_ + 2048, dB_ + 1024);                                  \
  } while (0)

  STAGE_B(0, 0);

  // per-thread row metadata + accumulators
  int rowAd[2][4];
#pragma unroll
  for (int mt = 0; mt < 2; ++mt)
#pragma unroll
    for (int r = 0; r < 4; ++r)
      rowAd[mt][r] = ad[rowBase + wr * 32 + mt * 16 + qd * 4 + r];

  float apA[2][4], apP[2][4];
#pragma unroll
  for (int mt = 0; mt < 2; ++mt)
#pragma unroll
    for (int r = 0; r < 4; ++r) {
      apA[mt][r] = 0.f;
      apP[mt][r] = 0.f;
    }

  VMCNT2();   // A's 4 loads done (tile0's 2 may remain in flight)
  BAR();      // all waves' A contributions staged

  // ---- one-time A fragment hoist (A region never rewritten) ----
  v8i afReg[2][2];
#pragma unroll
  for (int kk = 0; kk < 2; ++kk)
#pragma unroll
    for (int mt = 0; mt < 2; ++mt) {
      const int row = wr * 32 + mt * 16 + lq;
      const int gg  = kk * 8 + qd * 2;   // 16B group within 256B row
      i32x4* ph_ = reinterpret_cast<i32x4*>(&afReg[kk][mt]);
      ph_[0] = *reinterpret_cast<const i32x4*>(&smem[row * 256 + ((gg ^ (lq & 3)) << 4)]);
      ph_[1] = *reinterpret_cast<const i32x4*>(&smem[row * 256 + (((gg + 1) ^ (lq & 3)) << 4)]);
    }
  // no barrier: A region is read-only from here; slot1 untouched so far
  STAGE_B(1, 1);

  const int s0 = ((qd * 2) ^ (lq & 7)) << 4;      // B-frag slots (128B rows)
  const int s1 = ((qd * 2 + 1) ^ (lq & 7)) << 4;
  const f32x4 CZ = (f32x4){0.f, 0.f, 0.f, 0.f};

  for (int ct = 0; ct < 16; ++ct) {
    const int b0 = (2 * ct) % 3;        // slot of tile 2ct (kk0)
    const int b1 = (2 * ct + 1) % 3;    // slot of tile 2ct+1 (kk1)
    const int b2 = (2 * ct + 2) % 3;    // stage target (even phase)
    f32x4 c[2][2];
    float colB[2];
    int colAd[2];

    // ===== even phase: compute tile 2ct (kk=0), C-in = 0 =====
    VMCNT2();   // drains tile 2ct (and any older metas); tile 2ct+1 in flight
    BAR();
#pragma unroll
    for (int nt = 0; nt < 2; ++nt) {    // meta first (older than the stage)
      const int col = colBase + ct * 64 + wc * 32 + nt * 16 + lq;
      colB[nt]  = cbias[col];           // SIM_BIAS already folded in prep
      colAd[nt] = ad[col];
    }
    if (ct < 15) STAGE_B(2 * ct + 2, b2);
    {
      const unsigned char* Bh = &smem[16384 + b0 * 8192];
#pragma unroll
      for (int nt = 0; nt < 2; ++nt) {
        const int rb = (wc * 32 + nt * 16 + lq) * 128;
        v8i bf;
        i32x4* pb = reinterpret_cast<i32x4*>(&bf);
        pb[0] = *reinterpret_cast<const i32x4*>(&Bh[rb + s0]);
        pb[1] = *reinterpret_cast<const i32x4*>(&Bh[rb + s1]);
#pragma unroll
        for (int mt = 0; mt < 2; ++mt)
          c[mt][nt] = __builtin_amdgcn_mfma_scale_f32_16x16x128_f8f6f4(
              afReg[0][mt], bf, CZ, 0, 0, 0, SCALE1, 0, SCALE1);
      }
    }
    LGKM0();    // pin this phase's ds_reads inside the phase (rule #18)
    SCHEDB();

    // ===== odd phase: compute tile 2ct+1 (kk=1), accumulate + epilogue =====
    if (ct < 15) { VMCNT6(); } else { VMCNT0(); }   // drains tile 2ct+1
    BAR();
    if (ct < 15) STAGE_B(2 * ct + 3, b0);   // b0 freed by the barrier above
    {
      const unsigned char* Bh = &smem[16384 + b1 * 8192];
#pragma unroll
      for (int nt = 0; nt < 2; ++nt) {
        const int rb = (wc * 32 + nt * 16 + lq) * 128;
        v8i bf;
        i32x4* pb = reinterpret_cast<i32x4*>(&bf);
        pb[0] = *reinterpret_cast<const i32x4*>(&Bh[rb + s0]);
        pb[1] = *reinterpret_cast<const i32x4*>(&Bh[rb + s1]);
#pragma unroll
        for (int mt = 0; mt < 2; ++mt)
          c[mt][nt] = __builtin_amdgcn_mfma_scale_f32_16x16x128_f8f6f4(
              afReg[1][mt], bf, c[mt][nt], 0, 0, 0, SCALE1, 0, SCALE1);
      }
    }
    LGKM0();
    SCHEDB();

    // ---- epilogue for col-tile ct: exp2-accumulate into registers ----
#pragma unroll
    for (int mt = 0; mt < 2; ++mt) {
#pragma unroll
      for (int r = 0; r < 4; ++r) {
        float a = 0.f, p = 0.f;
#pragma unroll
        for (int nt = 0; nt < 2; ++nt) {
          const float e = __builtin_amdgcn_exp2f(fmaf(c[mt][nt][r], SIM_SCALE, colB[nt]));
          a += e;
          p += (colAd[nt] == rowAd[mt][r]) ? e : 0.f;
        }
        apA[mt][r] += a;
        apP[mt][r] += p;
      }
    }
  }
#undef STAGE_B

  // ---- final: fold the 16 lq lanes (same row per qd group), one atomic ----
#pragma unroll
  for (int mt = 0; mt < 2; ++mt) {
#pragma unroll
    for (int r = 0; r < 4; ++r) {
      float a = apA[mt][r], p = apP[mt][r];
#pragma unroll
      for (int m = 1; m < 16; m <<= 1) {
        a += __shfl_xor(a, m);
        p += __shfl_xor(p, m);
      }
      if (lq == 0) {
        const int row = rowBase + wr * 32 + mt * 16 + qd * 4 + r;
        atomicAdd(&g_all[row], a);
        atomicAdd(&g_pos[row], p);
      }
    }
  }
}

// ---------------------------------------------------------------------------
// Kernel 3: loss = mean over valid rows of log(g_all) - log(g_pos).
// ---------------------------------------------------------------------------
__global__ __launch_bounds__(1024) void reduce_kernel(const float* __restrict__ g_all,
                                                      const float* __restrict__ g_pos,
                                                      const int* __restrict__ pad,
                                                      float* __restrict__ out) {
  __shared__ float sS[16], sC[16];
  const int t = threadIdx.x;
  float s = 0.f, c = 0.f;
  const float4* ga4 = (const float4*)g_all;
  const float4* gp4 = (const float4*)g_pos;
  const int4*   pd4 = (const int4*)pad;
  for (int i = t; i < Nn / 4; i += 1024) {
    const float4 ga = ga4[i];
    const float4 gp = gp4[i];
    const int4   pd = pd4[i];
    if (pd.x) { s += __logf(ga.x) - __logf(gp.x); c += 1.f; }
    if (pd.y) { s += __logf(ga.y) - __logf(gp.y); c += 1.f; }
    if (pd.z) { s += __logf(ga.z) - __logf(gp.z); c += 1.f; }
    if (pd.w) { s += __logf(ga.w) - __logf(gp.w); c += 1.f; }
  }
#pragma unroll
  for (int m = 32; m >= 1; m >>= 1) {
    s += __shfl_xor(s, m);
    c += __shfl_xor(c, m);
  }
  if ((t & 63) == 0) { sS[t >> 6] = s; sC[t >> 6] = c; }
  __syncthreads();
  if (t == 0) {
    float S = 0.f, C = 0.f;
#pragma unroll
    for (int i = 0; i < 16; ++i) { S += sS[i]; C += sC[i]; }
    out[0] = S / fmaxf(C, 1.0f);
  }
}

extern "C" void kernel_launch(void* const* d_in, const int* in_sizes, int n_in,
                              void* d_out, int out_size, void* d_ws, size_t ws_size,
                              hipStream_t stream) {
  const float* logits = (const float*)d_in[0];
  const float* labels = (const float*)d_in[1];
  const int*   pad    = (const int*)d_in[2];
  const int*   ad     = (const int*)d_in[3];

  char* ws = (char*)d_ws;
  unsigned char* qb = (unsigned char*)(ws);             // 2 MiB (fp8)
  unsigned char* kb = (unsigned char*)(ws + 2097152);   // 2 MiB (fp8)
  float*  cb   = (float*)(ws + 4194304);                // 32 KiB
  float*  gAll = (float*)(ws + 4227072);                // 32 KiB
  float*  gPos = (float*)(ws + 4259840);                // 32 KiB
  float*  out  = (float*)d_out;

  prep_kernel<<<4096, 256, 0, stream>>>(logits, labels, pad, qb, kb, cb, gAll, gPos);
  gemm_lse_kernel<<<dim3(128, 8), 256, 0, stream>>>(qb, kb, cb, ad, gAll, gPos);
  reduce_kernel<<<1, 1024, 0, stream>>>(gAll, gPos, pad, out);
}